// Round 18
// baseline (85.477 us; speedup 1.0000x reference)
//
#include <hip/hip_runtime.h>
#include <stdint.h>

typedef unsigned short u16;
typedef unsigned int u32;

#define L_SEQ 2048
#define DMODEL 1024
#define NHEAD 16

using f32x4 = __attribute__((ext_vector_type(4))) float;
using f32x16 = __attribute__((ext_vector_type(16))) float;
using s16x8 = __attribute__((ext_vector_type(8))) short;
using s16x4 = __attribute__((ext_vector_type(4))) short;

__device__ __forceinline__ u16 f2b(float f) {
    union { float f; uint32_t u; } v; v.f = f;
    uint32_t r = v.u + 0x7fffu + ((v.u >> 16) & 1u);
    return (u16)(r >> 16);
}

__device__ __forceinline__ float b2f(u16 x) {
    union { uint32_t u; float f; } v; v.u = ((uint32_t)x) << 16;
    return v.f;
}

__device__ __forceinline__ u32 pk2(float a, float b) {
    return (u32)f2b(a) | ((u32)f2b(b) << 16);
}

__device__ __forceinline__ u32 cvtpk(float lo, float hi_) {
    u32 r;
    asm("v_cvt_pk_bf16_f32 %0, %1, %2" : "=v"(r) : "v"(lo), "v"(hi_));
    return r;
}

__device__ __forceinline__ void gld16(const void* g, void* l) {
    __builtin_amdgcn_global_load_lds(
        (__attribute__((address_space(1))) void*)(uintptr_t)g,
        (__attribute__((address_space(3))) void*)(uintptr_t)l,
        16, 0, 0);
}

// ---------------- pure streaming converts (verified R16) ----------------
__global__ __launch_bounds__(256)
void k_conv(const float* __restrict__ x, const float* __restrict__ wq,
            const float* __restrict__ wk, const float* __restrict__ wv,
            const float* __restrict__ wo, const float* __restrict__ wp,
            const float* __restrict__ bp,
            u16* __restrict__ xb, u16* __restrict__ wqb, u16* __restrict__ wkb,
            u16* __restrict__ wvb, u16* __restrict__ wob, u16* __restrict__ wpb,
            float* __restrict__ bpPad) {
    const int NX = L_SEQ * DMODEL / 8;      // 262144
    const int NW = DMODEL * DMODEL / 8;     // 131072
    const int NCONV = (NX + 4 * NW) / 256;  // 3072
    const int NP = 32 * DMODEL / 8;         // 4096
    const int bid = blockIdx.x, tid = threadIdx.x;

    if (bid < NCONV) {
        int i = bid * 256 + tid;
        const float* src; u16* dst; int j;
        if (i < NX) { src = x; dst = xb; j = i; }
        else {
            int t = i - NX; int sel = t >> 17; j = t & (NW - 1);
            src = (sel == 0) ? wq : (sel == 1) ? wk : (sel == 2) ? wv : wo;
            dst = (sel == 0) ? wqb : (sel == 1) ? wkb : (sel == 2) ? wvb : wob;
        }
        const float4* s4 = (const float4*)src;
        float4 a = s4[2 * j], b = s4[2 * j + 1];
        union { s16x8 v; u16 u[8]; } o;
        o.u[0] = f2b(a.x); o.u[1] = f2b(a.y); o.u[2] = f2b(a.z); o.u[3] = f2b(a.w);
        o.u[4] = f2b(b.x); o.u[5] = f2b(b.y); o.u[6] = f2b(b.z); o.u[7] = f2b(b.w);
        ((s16x8*)dst)[j] = o.v;
        return;
    }
    if (bid < NCONV + 32) {
        int i2 = (bid - NCONV) * 256 + tid;
        union { s16x8 v; u16 u[8]; } o;
        if (i2 < NP) {
            const float4* s4 = (const float4*)wp;
            float4 a = s4[2 * i2], b = s4[2 * i2 + 1];
            o.u[0] = f2b(a.x); o.u[1] = f2b(a.y); o.u[2] = f2b(a.z); o.u[3] = f2b(a.w);
            o.u[4] = f2b(b.x); o.u[5] = f2b(b.y); o.u[6] = f2b(b.z); o.u[7] = f2b(b.w);
        } else {
#pragma unroll
            for (int j = 0; j < 8; ++j) o.u[j] = 0;
        }
        ((s16x8*)wpb)[i2] = o.v;
        return;
    }
    if (tid < 64) bpPad[tid] = (tid < 32) ? bp[tid] : 0.f;
}

// ---------------- bf16 B^T GEMM, BM=128 BN=64 BK=64 (verified R9/R10/R16) ----------------
template <int MODE>
__global__ __launch_bounds__(256, 2)
void k_gemm64(const u16* __restrict__ A,
              const u16* __restrict__ B0, const u16* __restrict__ B1, const u16* __restrict__ B2,
              const u16* __restrict__ B3,
              const float* __restrict__ c0, const float* __restrict__ c1, const float* __restrict__ c2,
              const float* __restrict__ c3,
              void* __restrict__ Out, u16* __restrict__ Vt, float* __restrict__ Ph,
              int ldo, int K) {
    __shared__ u16 As[128 * 64];
    __shared__ u16 Bs[64 * 64];
    const int tid = threadIdx.x;
    const int w = tid >> 6, lane = tid & 63;
    const int wr = w >> 1, wc = w & 1;
    const int u = lane & 15, g = lane >> 4;
    const int lr = lane >> 3;
    const int cb = lane & 7;
    const int mt = blockIdx.x, nt = blockIdx.y;
    const int seg = nt >> 4, ntl = nt & 15;
    const u16* Bp = (seg == 0) ? B0 : (seg == 1) ? B1 : (seg == 2) ? B2 : B3;
    const float* biasp = (seg == 0) ? c0 : (seg == 1) ? c1 : (seg == 2) ? c2 : c3;

    const u16* Ab = A + (size_t)(mt * 128 + w * 32) * K;
    const u16* Bb = Bp + (size_t)(ntl * 64) * K;
    char* asB = (char*)As;
    char* bsB = (char*)Bs;

    f32x4 acc[4][2] = {};

    for (int k0 = 0; k0 < K; k0 += 64) {
#pragma unroll
        for (int c = 0; c < 4; ++c)
            gld16(Ab + (size_t)(c * 8 + lr) * K + k0 + ((cb ^ lr) * 8),
                  asB + (w * 32 + c * 8) * 128);
#pragma unroll
        for (int t = 0; t < 2; ++t)
            gld16(Bb + (size_t)(t * 32 + w * 8 + lr) * K + k0 + ((cb ^ lr) * 8),
                  bsB + t * 4096 + w * 1024);
        __syncthreads();
        const int x0 = (g * 16) ^ ((u & 7) << 4);
#pragma unroll
        for (int ks = 0; ks < 2; ++ks) {
            s16x8 af[4], bf[2];
#pragma unroll
            for (int i = 0; i < 4; ++i)
                af[i] = *(const s16x8*)(asB + (wr * 64 + i * 16 + u) * 128 + (x0 ^ (ks * 64)));
#pragma unroll
            for (int j = 0; j < 2; ++j)
                bf[j] = *(const s16x8*)(bsB + (wc * 32 + j * 16 + u) * 128 + (x0 ^ (ks * 64)));
#pragma unroll
            for (int i = 0; i < 4; ++i)
#pragma unroll
                for (int j = 0; j < 2; ++j)
                    acc[i][j] = __builtin_amdgcn_mfma_f32_16x16x32_bf16(af[i], bf[j], acc[i][j], 0, 0, 0);
        }
        __syncthreads();
    }

#pragma unroll
    for (int i = 0; i < 4; ++i) {
#pragma unroll
        for (int j = 0; j < 2; ++j) {
            const int row0 = mt * 128 + wr * 64 + i * 16 + g * 4;
            const int col = nt * 64 + wc * 32 + j * 16 + u;
            const int colseg = ntl * 64 + wc * 32 + j * 16 + u;
            const float bias = biasp[colseg];
            if (MODE == 0 && seg == 2) {
                union { s16x4 v; u16 us[4]; } p;
#pragma unroll
                for (int r = 0; r < 4; ++r) p.us[r] = f2b(acc[i][j][r] + bias);
                *(s16x4*)(Vt + (size_t)colseg * L_SEQ + row0) = p.v;
            } else if (MODE == 0 && seg == 3) {
#pragma unroll
                for (int r = 0; r < 4; ++r)
                    Ph[(size_t)(row0 + r) * 64 + colseg] = acc[i][j][r] + bias;
            } else {
#pragma unroll
                for (int r = 0; r < 4; ++r) {
                    float val = acc[i][j][r] + bias;
                    if (MODE == 1)
                        ((float*)Out)[(size_t)(row0 + r) * ldo + col] = val;
                    else
                        ((u16*)Out)[(size_t)(row0 + r) * ldo + col] = f2b(val);
                }
            }
        }
    }
}

// ---------------- normalize phase pairs (verified R16) ----------------
__global__ __launch_bounds__(256)
void k_norm(const float* __restrict__ ph, float2* __restrict__ CSph) {
    int t = blockIdx.x * 256 + threadIdx.x;   // 32768
    int m = t >> 4, h = t & 15;
    float c = ph[(size_t)m * 64 + 2 * h];
    float s = ph[(size_t)m * 64 + 2 * h + 1];
    float inv = 1.0f / fmaxf(sqrtf(c * c + s * s), 1e-6f);
    CSph[(size_t)h * L_SEQ + m] = make_float2(c * inv, s * inv);
}

// ---------------- fused attention v12: fixed-m + depth-3 counted-vmcnt pipeline (T3/T4) ----------------
// R17 math byte-identical. 3 K/V LDS slots; per-iteration waits are counted
// (vmcnt(8)/(4)/(0)), never a full drain: loads get a 2-iteration latency
// budget. Phase pairs pre-staged in LDS so the loop has NO vmem except the
// 4 prefetch gld16s (keeps the manual vmcnt count exact).
__global__ __launch_bounds__(256, 2)
void k_attn(const u16* __restrict__ QKV, const u16* __restrict__ VtG,
            const float2* __restrict__ CSph,
            const float* __restrict__ gamma,
            u16* __restrict__ Op0, u16* __restrict__ Op1, u16* __restrict__ Op2,
            float2* __restrict__ ML) {
    const int h = blockIdx.y;
    const int s = blockIdx.z;
    const int qb = blockIdx.x * 128;
    const int tid = threadIdx.x;
    const int ww = tid >> 6, lane = tid & 63;
    const int q5 = lane & 31, hi = lane >> 5;
    const int ld = 3 * DMODEL;
    const int NT = (s == 2) ? 10 : 11;    // 11+11+10 = 32 tiles
    const int kbase = s * 11 * 64;
    const int BUF = 64 * 64 * 2;          // 8 KB per slot
    const float MFIX = 8.0f;

    __shared__ u16 Ks[3][64 * 64];        // 3-slot pipeline
    __shared__ u16 Vs[3][64 * 64];
    __shared__ u32 csLDS[11 * 32 * 2];    // per-tile phase pairs (pre-scaled, packed)

    const float LOG2E = 1.44269504088896f;
    const float sig = 1.0f / (1.0f + __expf(-gamma[h]));
    const float gateA = 0.64f * sig;
    const float SC2 = 0.125f * LOG2E;

    const u16* Qp = QKV + h * 64;
    const u16* Kp = QKV + DMODEL + h * 64 + (size_t)kbase * ld;
    const u16* VtH = VtG + (size_t)h * 64 * L_SEQ + kbase;
    const float2* CS = CSph + (size_t)h * L_SEQ;

    const int qrow = qb + ww * 32 + q5;
    s16x8 bq[4];
#pragma unroll
    for (int d = 0; d < 4; ++d)
        bq[d] = *(const s16x8*)(Qp + (size_t)qrow * ld + d * 16 + hi * 8);
    s16x8 bcs;
    {
        float2 cs = CS[qrow];
        union { u32 w[4]; s16x8 v; } t = {};
        t.w[0] = hi ? 0u : pk2(cs.x, cs.y);
        bcs = t.v;
    }

    unsigned dstOff[2]; size_t srcK[2], srcV[2];
#pragma unroll
    for (int t = 0; t < 2; ++t) {
        int ci = (ww * 2 + t) * 64 + lane;
        int row = ci >> 3, cb = ci & 7;
        dstOff[t] = (unsigned)((ww * 2 + t) * 1024);
        srcK[t] = (size_t)row * ld + (size_t)((cb ^ (row & 7)) * 8);
        srcV[t] = (size_t)row * L_SEQ + (size_t)((cb ^ (row & 7)) * 8);
    }
    char* ksBase = (char*)Ks;
    char* vsBase = (char*)Vs;
    const int swz = (q5 & 7) << 4;

    // prologue: issue tiles 0..2 into slots 0..2 (12 loads)
#pragma unroll
    for (int pt = 0; pt < 3; ++pt) {
        if (pt < NT) {
            const u16* Kn = Kp + (size_t)pt * 64 * ld;
            const u16* Vn = VtH + (size_t)pt * 64;
#pragma unroll
            for (int t = 0; t < 2; ++t) {
                gld16(Kn + srcK[t], ksBase + pt * BUF + dstOff[t]);
                gld16(Vn + srcV[t], vsBase + pt * BUF + dstOff[t]);
            }
        }
    }
    // pre-stage per-tile phase pairs into LDS (vmem here is drained below)
    for (int t = tid; t < NT * 32; t += 256) {
        int kt = t >> 5, qq = t & 31;
        float2 c0 = CS[kbase + kt * 64 + qq];
        float2 c1 = CS[kbase + kt * 64 + 32 + qq];
        csLDS[t * 2] = pk2(gateA * c0.x, gateA * c0.y);
        csLDS[t * 2 + 1] = pk2(gateA * c1.x, gateA * c1.y);
    }
    __syncthreads();   // full drain once; loop vmcnt counts only loop gld16s

    float lsum = 0.f;
    f32x16 oA = {}, oB = {};
    int cur = 0;

    for (int kt = 0; kt < NT; ++kt) {
        const char* kCur = ksBase + cur * BUF;
        const char* vCur = vsBase + cur * BUF;

        // tile kt ready: allow 4 loads per not-yet-needed tile to stay in flight
        if (kt + 2 < NT)      asm volatile("s_waitcnt vmcnt(8)" ::: "memory");
        else if (kt + 1 < NT) asm volatile("s_waitcnt vmcnt(4)" ::: "memory");
        else                  asm volatile("s_waitcnt vmcnt(0)" ::: "memory");
        __builtin_amdgcn_sched_barrier(0);
        __builtin_amdgcn_s_barrier();
        __builtin_amdgcn_sched_barrier(0);

        // phase A-fragments from the LDS table
        s16x8 acs0, acs1;
        {
            u32 w0 = csLDS[(kt * 32 + q5) * 2];
            u32 w1 = csLDS[(kt * 32 + q5) * 2 + 1];
            union { u32 w[4]; s16x8 v; } t0 = {}, t1 = {};
            t0.w[0] = hi ? 0u : w0;
            t1.w[0] = hi ? 0u : w1;
            acs0 = t0.v; acs1 = t1.v;
        }

        // ---- S^T = K Q^T + fused phase bias (R12/R14-verified) ----
        f32x16 sf0 = {}, sf1 = {};
        __builtin_amdgcn_s_setprio(1);
#pragma unroll
        for (int d = 0; d < 4; ++d) {
            s16x8 ak0 = *(const s16x8*)(kCur + q5 * 128 + ((d * 32 + hi * 16) ^ swz));
            s16x8 ak1 = *(const s16x8*)(kCur + (32 + q5) * 128 + ((d * 32 + hi * 16) ^ swz));
            sf0 = __builtin_amdgcn_mfma_f32_32x32x16_bf16(ak0, bq[d], sf0, 0, 0, 0);
            sf1 = __builtin_amdgcn_mfma_f32_32x32x16_bf16(ak1, bq[d], sf1, 0, 0, 0);
        }
        sf0 = __builtin_amdgcn_mfma_f32_32x32x16_bf16(acs0, bcs, sf0, 0, 0, 0);
        sf1 = __builtin_amdgcn_mfma_f32_32x32x16_bf16(acs1, bcs, sf1, 0, 0, 0);
        __builtin_amdgcn_s_setprio(0);

        // ---- P = exp2(S*SC2 - MFIX) ----
#pragma unroll
        for (int r = 0; r < 16; ++r) sf0[r] = __builtin_amdgcn_exp2f(__builtin_fmaf(sf0[r], SC2, -MFIX));
#pragma unroll
        for (int r = 0; r < 16; ++r) sf1[r] = __builtin_amdgcn_exp2f(__builtin_fmaf(sf1[r], SC2, -MFIX));

        // ---- l: lane-local accumulation ----
#pragma unroll
        for (int r = 0; r < 16; ++r) lsum += sf0[r] + sf1[r];

        // ---- PV with in-register P fragments (R14-verified) ----
        __builtin_amdgcn_s_setprio(1);
#define PV_SUBTILE(SFV, HALF, SU)                                                              \
        {                                                                                      \
            u32 Aw  = cvtpk(SFV[(HALF) * 8 + 0], SFV[(HALF) * 8 + 1]);                         \
            u32 A2w = cvtpk(SFV[(HALF) * 8 + 2], SFV[(HALF) * 8 + 3]);                         \
            u32 Bw  = cvtpk(SFV[(HALF) * 8 + 4], SFV[(HALF) * 8 + 5]);                         \
            u32 B2w = cvtpk(SFV[(HALF) * 8 + 6], SFV[(HALF) * 8 + 7]);                         \
            u32 xw  = (u32)__shfl_xor((int)(hi ? Aw : Bw), 32);                                \
            u32 x2w = (u32)__shfl_xor((int)(hi ? A2w : B2w), 32);                              \
            union { u32 w[4]; s16x8 v; } pa;                                                   \
            pa.w[0] = hi ? xw : Aw;   pa.w[1] = hi ? x2w : A2w;                                \
            pa.w[2] = hi ? Bw : xw;   pa.w[3] = hi ? B2w : x2w;                                \
            s16x8 bvA = *(const s16x8*)(vCur + q5 * 128 + (((SU) * 32 + hi * 16) ^ swz));      \
            s16x8 bvB = *(const s16x8*)(vCur + (32 + q5) * 128 + (((SU) * 32 + hi * 16) ^ swz));\
            oA = __builtin_amdgcn_mfma_f32_32x32x16_bf16(pa.v, bvA, oA, 0, 0, 0);              \
            oB = __builtin_amdgcn_mfma_f32_32x32x16_bf16(pa.v, bvB, oB, 0, 0, 0);              \
        }
        PV_SUBTILE(sf0, 0, 0)
        PV_SUBTILE(sf0, 1, 1)
        PV_SUBTILE(sf1, 0, 2)
        PV_SUBTILE(sf1, 1, 3)
#undef PV_SUBTILE
        __builtin_amdgcn_s_setprio(0);

        // all waves done reading slot `cur` -> safe to reuse it for tile kt+3
        __builtin_amdgcn_s_barrier();
        __builtin_amdgcn_sched_barrier(0);
        if (kt + 3 < NT) {
            const u16* Kn = Kp + (size_t)(kt + 3) * 64 * ld;
            const u16* Vn = VtH + (size_t)(kt + 3) * 64;
            char* kN = ksBase + cur * BUF;
            char* vN = vsBase + cur * BUF;
#pragma unroll
            for (int t = 0; t < 2; ++t) {
                gld16(Kn + srcK[t], kN + dstOff[t]);
                gld16(Vn + srcV[t], vN + dstOff[t]);
            }
        }
        cur = (cur == 2) ? 0 : cur + 1;
    }

    // ---- epilogue ----
    lsum += __shfl_xor(lsum, 32);

    u16* OpS = (s == 0) ? Op0 : (s == 1) ? Op1 : Op2;
    float2* MLS = ML + (size_t)(s * NHEAD + h) * L_SEQ;
#pragma unroll
    for (int r = 0; r < 16; ++r) {
        int q_r = qb + ww * 32 + (r & 3) + 8 * (r >> 2) + 4 * hi;
        OpS[(size_t)q_r * DMODEL + h * 64 + q5] = f2b(oA[r]);
        OpS[(size_t)q_r * DMODEL + h * 64 + 32 + q5] = f2b(oB[r]);
    }
    if (hi == 0)
        MLS[qb + ww * 32 + q5] = make_float2(MFIX, lsum);
}

// ---------------- 3-way split combine (verified R15/R16) ----------------
__global__ __launch_bounds__(256)
void k_comb(const u16* __restrict__ Op0, const u16* __restrict__ Op1,
            const u16* __restrict__ Op2, const float2* __restrict__ ML,
            u16* __restrict__ attnb) {
    int t = blockIdx.x * 256 + threadIdx.x;   // 262144 total
    int row = t >> 7, cg = t & 127;
    int col0 = cg * 8, h = cg >> 3;
    float2 ml0 = ML[(size_t)h * L_SEQ + row];
    float2 ml1 = ML[(size_t)(NHEAD + h) * L_SEQ + row];
    float2 ml2 = ML[(size_t)(2 * NHEAD + h) * L_SEQ + row];
    float M = fmaxf(fmaxf(ml0.x, ml1.x), ml2.x);
    float a0 = __builtin_amdgcn_exp2f(ml0.x - M);
    float a1 = __builtin_amdgcn_exp2f(ml1.x - M);
    float a2 = __builtin_amdgcn_exp2f(ml2.x - M);
    float inv = 1.0f / (ml0.y * a0 + ml1.y * a1 + ml2.y * a2);
    a0 *= inv; a1 *= inv; a2 *= inv;
    union { s16x8 v; u16 us[8]; } o0, o1, o2, wout;
    size_t off = (size_t)row * DMODEL + col0;
    o0.v = *(const s16x8*)(Op0 + off);
    o1.v = *(const s16x8*)(Op1 + off);
    o2.v = *(const s16x8*)(Op2 + off);   // Op2 == attnb (read-before-write, same thread)
#pragma unroll
    for (int j = 0; j < 8; ++j)
        wout.us[j] = f2b(b2f(o0.us[j]) * a0 + b2f(o1.us[j]) * a1 + b2f(o2.us[j]) * a2);
    *(s16x8*)(attnb + off) = wout.v;
}

extern "C" void kernel_launch(void* const* d_in, const int* in_sizes, int n_in,
                              void* d_out, int out_size, void* d_ws, size_t ws_size,
                              hipStream_t stream) {
    const float* x  = (const float*)d_in[0];
    const float* Wq = (const float*)d_in[1];
    const float* bq = (const float*)d_in[2];
    const float* Wk = (const float*)d_in[3];
    const float* bk = (const float*)d_in[4];
    const float* Wv = (const float*)d_in[5];
    const float* bv = (const float*)d_in[6];
    const float* Wo = (const float*)d_in[7];
    const float* bo = (const float*)d_in[8];
    const float* Wp = (const float*)d_in[9];
    const float* bp = (const float*)d_in[10];
    const float* gamma = (const float*)d_in[11];
    float* out = (float*)d_out;

    char* ws = (char*)d_ws;
    u16* xb = (u16*)ws;   ws += (size_t)L_SEQ * DMODEL * 2;       // 4 MB
    u16* wqb = (u16*)ws;  ws += (size_t)DMODEL * DMODEL * 2;      // 2 MB
    u16* wkb = (u16*)ws;  ws += (size_t)DMODEL * DMODEL * 2;      // 2 MB
    u16* wvb = (u16*)ws;  ws += (size_t)DMODEL * DMODEL * 2;      // 2 MB
    u16* wob = (u16*)ws;  ws += (size_t)DMODEL * DMODEL * 2;      // 2 MB
    u16* qkv = (u16*)ws;  ws += (size_t)L_SEQ * 3 * DMODEL * 2;   // 12 MB
    u16* attnb = (u16*)ws; ws += (size_t)L_SEQ * DMODEL * 2;      // 4 MB
    u16* VtG = (u16*)ws;  ws += (size_t)DMODEL * L_SEQ * 2;       // 4 MB
    float2* CSph = (float2*)ws; ws += (size_t)NHEAD * L_SEQ * 8;  // 256 KB
    u16* wpb = (u16*)ws;  ws += (size_t)64 * DMODEL * 2;          // 128 KB
    float* bpPad = (float*)ws; ws += 64 * 4;                      // 256 B
    float* phtmp = (float*)ws; ws += (size_t)L_SEQ * 64 * 4;      // 512 KB

    // overlays (dead after QKV GEMM): Op0 = xb, Op1 = wqb+wkb, ML = wvb.
    // Op2 lives in attnb (combined in-place by k_comb).
    u16* Op0 = xb;
    u16* Op1 = wqb;
    u16* Op2 = attnb;
    float2* ML = (float2*)wvb;

    // pure streaming converts
    k_conv<<<3072 + 32 + 1, 256, 0, stream>>>(x, Wq, Wk, Wv, Wo, Wp, bp,
                                              xb, wqb, wkb, wvb, wob, wpb, bpPad);

    // fused QKV + phase projection
    k_gemm64<0><<<dim3(16, 49), 256, 0, stream>>>(xb, wqb, wkb, wvb, wpb,
                                                  bq, bk, bv, bpPad,
                                                  (void*)qkv, VtG, phtmp, 3 * DMODEL, DMODEL);

    // normalize phase pairs -> CSph
    k_norm<<<L_SEQ * NHEAD / 256, 256, 0, stream>>>(phtmp, CSph);

    // 3-way kv-split attention -> partials (fixed-m softmax, depth-3 pipeline)
    k_attn<<<dim3(L_SEQ / 128, NHEAD, 3), 256, 0, stream>>>(qkv, VtG, CSph, gamma,
                                                            Op0, Op1, Op2, ML);

    // merge splits -> attnb bf16 (Op2 in-place)
    k_comb<<<L_SEQ * DMODEL / 8 / 256, 256, 0, stream>>>(Op0, Op1, Op2, ML, attnb);

    // output projection -> d_out f32
    k_gemm64<1><<<dim3(16, 16), 256, 0, stream>>>(attnb, wob, wob, wob, wob,
                                                  bo, bo, bo, bo,
                                                  (void*)out, nullptr, nullptr, DMODEL, DMODEL);
}